// Round 10
// baseline (144.911 us; speedup 1.0000x reference)
//
#include <hip/hip_runtime.h>

#define SS 1024
#define BB 4096
#define HH 8
#define XSTRIDE (BB * HH)   // floats per timestep slice

typedef float f32x2 __attribute__((ext_vector_type(2)));

// DPP cross-lane (VALU pipe): xor1/xor2 via quad_perm, xor7 via row_half_mirror.
__device__ __forceinline__ int dpp_x1(int v) { return __builtin_amdgcn_mov_dpp(v, 0xB1, 0xF, 0xF, true); }
__device__ __forceinline__ int dpp_x2(int v) { return __builtin_amdgcn_mov_dpp(v, 0x4E, 0xF, 0xF, true); }
__device__ __forceinline__ int dpp_x7(int v) { return __builtin_amdgcn_mov_dpp(v, 0x141, 0xF, 0xF, true); }

// Butterfly register m holds v[j ^ MK[m]]; BOTH weight sets pre-permuted to match.
__device__ __constant__ int MK_[8] = {0, 1, 2, 3, 7, 6, 5, 4};

// Pinned scalar prefetch: 4B/lane, wave = 256B fully coalesced, one distinct
// value per lane (kills rounds 0-9's 8x-replicated float4 buffers: 128 VGPRs
// -> 16, which is what forced the RA's hidden AGPR shuttling).
#define ALOADD(DST, PTR) asm volatile("global_load_dword %0, %1, off" : "=v"(DST) : "v"(PTR))

#define WAITV(N) do {                                                                  \
    asm volatile("s_waitcnt vmcnt(" #N ")" ::: "memory");                              \
    __builtin_amdgcn_sched_barrier(0);                                                 \
} while (0)

// Butterfly one scalar across the 8-lane group into 4 MK-ordered f32x2 pairs.
#define BFLY8(SRC, DV) do {                                                            \
    const int b0_ = __float_as_int(SRC);                                               \
    const int b1_ = dpp_x1(b0_);                                                       \
    const int b2_ = dpp_x2(b0_);                                                       \
    const int b3_ = dpp_x2(b1_);                                                       \
    const int b4_ = dpp_x7(b0_);                                                       \
    const int b5_ = dpp_x7(b1_);                                                       \
    const int b6_ = dpp_x7(b2_);                                                       \
    const int b7_ = dpp_x7(b3_);                                                       \
    DV[0] = (f32x2){(SRC), __int_as_float(b1_)};                                       \
    DV[1] = (f32x2){__int_as_float(b2_), __int_as_float(b3_)};                         \
    DV[2] = (f32x2){__int_as_float(b4_), __int_as_float(b5_)};                         \
    DV[3] = (f32x2){__int_as_float(b6_), __int_as_float(b7_)};                         \
} while (0)

// Full X pre-activation for step V (head steps 0,1). Weights PRE-SCALED:
// r/z rows by -log2(e), n rows by +2*log2(e); x-weights MK-permuted like h's.
#define XFULL(BUF, V) do {                                                             \
    f32x2 xv_[4];                                                                      \
    BFLY8(BUF[V], xv_);                                                                \
    f32x2 sr_ = {bias_r, 0.0f}, sz_ = {bias_z, 0.0f}, sn_ = {bni_s, 0.0f};             \
    _Pragma("unroll")                                                                  \
    for (int p_ = 0; p_ < 4; ++p_) {                                                   \
        sr_ = __builtin_elementwise_fma(xv_[p_], wri[p_], sr_);                        \
        sz_ = __builtin_elementwise_fma(xv_[p_], wzi[p_], sz_);                        \
        sn_ = __builtin_elementwise_fma(xv_[p_], wni[p_], sn_);                        \
    }                                                                                  \
    xr[(V)] = sr_.x + sr_.y; xz[(V)] = sz_.x + sz_.y; xn[(V)] = sn_.x + sn_.y;         \
} while (0)

// One 8-step group: R-steps with X(u+2) lexically woven into the R-chain's
// transcendental stall windows (round 7's proven pattern; no rigid SBs --
// with register pressure fixed the scheduler can do the interleave itself).
#define GROUP(BUF, SBASE) do {                                                         \
    XFULL(BUF, 0);                                                                     \
    XFULL(BUF, 1);                                                                     \
    _Pragma("unroll")                                                                  \
    for (int u = 0; u < 8; ++u) {                                                      \
        /* S1: h-side dots (12 pk_fma, 3 independent chains) */                        \
        f32x2 hr2 = {xr[u], 0.0f}, hz2 = {xz[u], 0.0f}, hn2 = {bnh_s, 0.0f};           \
        _Pragma("unroll")                                                              \
        for (int p_ = 0; p_ < 4; ++p_) {                                               \
            hr2 = __builtin_elementwise_fma(hv2[p_], wrh[p_], hr2);                    \
            hz2 = __builtin_elementwise_fma(hv2[p_], wzh[p_], hz2);                    \
            hn2 = __builtin_elementwise_fma(hv2[p_], wnh[p_], hn2);                    \
        }                                                                              \
        const float srr = hr2.x + hr2.y;                                               \
        const float szz = hz2.x + hz2.y;                                               \
        const float snn = hn2.x + hn2.y;                                               \
        const bool W = (u + 2 < 8);                                                    \
        f32x2 xv_[4], sr_, sz_, sn_;                                                   \
        if (W) {   /* X(u+2) part 1: butterfly + first 6 pk_fma */                     \
            BFLY8(BUF[u + 2], xv_);                                                    \
            sr_ = (f32x2){bias_r, 0.0f}; sz_ = (f32x2){bias_z, 0.0f};                  \
            sn_ = (f32x2){bni_s, 0.0f};                                                \
            sr_ = __builtin_elementwise_fma(xv_[0], wri[0], sr_);                      \
            sz_ = __builtin_elementwise_fma(xv_[0], wzi[0], sz_);                      \
            sn_ = __builtin_elementwise_fma(xv_[0], wni[0], sn_);                      \
            sr_ = __builtin_elementwise_fma(xv_[1], wri[1], sr_);                      \
            sz_ = __builtin_elementwise_fma(xv_[1], wzi[1], sz_);                      \
            sn_ = __builtin_elementwise_fma(xv_[1], wni[1], sn_);                      \
        }                                                                              \
        const float er = __builtin_amdgcn_exp2f(srr);                                  \
        const float ez = __builtin_amdgcn_exp2f(szz);                                  \
        if (W) {   /* X(u+2) part 2: last 6 pk_fma */                                  \
            sr_ = __builtin_elementwise_fma(xv_[2], wri[2], sr_);                      \
            sz_ = __builtin_elementwise_fma(xv_[2], wzi[2], sz_);                      \
            sn_ = __builtin_elementwise_fma(xv_[2], wni[2], sn_);                      \
            sr_ = __builtin_elementwise_fma(xv_[3], wri[3], sr_);                      \
            sz_ = __builtin_elementwise_fma(xv_[3], wzi[3], sz_);                      \
            sn_ = __builtin_elementwise_fma(xv_[3], wni[3], sn_);                      \
        }                                                                              \
        const float r_ = __builtin_amdgcn_rcpf(1.0f + er);                             \
        const float z_ = __builtin_amdgcn_rcpf(1.0f + ez);                             \
        if (W) {   /* X(u+2) reduce */                                                 \
            xr[u + 2] = sr_.x + sr_.y;                                                 \
            xz[u + 2] = sz_.x + sz_.y;                                                 \
            xn[u + 2] = sn_.x + sn_.y;                                                 \
        }                                                                              \
        const float en = __builtin_amdgcn_exp2f(fmaf(r_, snn, xn[u]));                 \
        const float n_ = fmaf(-2.0f, __builtin_amdgcn_rcpf(1.0f + en), 1.0f);          \
        h = n_ + z_ * (h - n_);                                                        \
        const int hb_ = __float_as_int(h);                                             \
        const int t1_ = dpp_x1(hb_);                                                   \
        const int t2_ = dpp_x2(hb_);                                                   \
        const int t3_ = dpp_x2(t1_);                                                   \
        const int t4_ = dpp_x7(hb_);                                                   \
        const int t5_ = dpp_x7(t1_);                                                   \
        const int t6_ = dpp_x7(t2_);                                                   \
        const int t7_ = dpp_x7(t3_);                                                   \
        hv2[0] = (f32x2){h, __int_as_float(t1_)};                                      \
        hv2[1] = (f32x2){__int_as_float(t2_), __int_as_float(t3_)};                    \
        hv2[2] = (f32x2){__int_as_float(t4_), __int_as_float(t5_)};                    \
        hv2[3] = (f32x2){__int_as_float(t6_), __int_as_float(t7_)};                    \
        __builtin_nontemporal_store(h, &op[(size_t)((SBASE) + u) * XSTRIDE]);          \
    }                                                                                  \
} while (0)

// 8 pinned dword loads = one 8-step group (1 per step).
#define LOADG(BUF, GRP) do {                                                           \
    const float* bp_ = xq + (size_t)(GRP) * 8 * XSTRIDE;                               \
    _Pragma("unroll")                                                                  \
    for (int u_ = 0; u_ < 8; ++u_) ALOADD(BUF[u_], bp_ + (size_t)u_ * XSTRIDE);        \
} while (0)

// 8 lanes per batch element, 8 batches per wave, 512 waves (2/CU).
__global__ __launch_bounds__(64, 1) void gru_kernel(
    const float* __restrict__ x,
    const float* __restrict__ w_ih,
    const float* __restrict__ w_hh,
    const float* __restrict__ b_ih,
    const float* __restrict__ b_hh,
    float* __restrict__ out)
{
    const int lane = threadIdx.x;
    const int j = lane & 7;

    const float SR = -1.4426950408889634f;     // -log2(e): sigmoid scale
    const float SN = 2.8853900817779268f;      // 2*log2(e): tanh scale

    // BOTH weight sets MK-permuted (columns j ^ MK[m]) to match butterfly order.
    f32x2 wri[4], wzi[4], wni[4], wrh[4], wzh[4], wnh[4];
    #pragma unroll
    for (int p = 0; p < 4; ++p) {
        const int c0 = j ^ MK_[2 * p], c1 = j ^ MK_[2 * p + 1];
        wri[p] = (f32x2){SR * w_ih[j * 8 + c0],        SR * w_ih[j * 8 + c1]};
        wzi[p] = (f32x2){SR * w_ih[(8 + j) * 8 + c0],  SR * w_ih[(8 + j) * 8 + c1]};
        wni[p] = (f32x2){SN * w_ih[(16 + j) * 8 + c0], SN * w_ih[(16 + j) * 8 + c1]};
        wrh[p] = (f32x2){SR * w_hh[j * 8 + c0],        SR * w_hh[j * 8 + c1]};
        wzh[p] = (f32x2){SR * w_hh[(8 + j) * 8 + c0],  SR * w_hh[(8 + j) * 8 + c1]};
        wnh[p] = (f32x2){SN * w_hh[(16 + j) * 8 + c0], SN * w_hh[(16 + j) * 8 + c1]};
    }
    const float bias_r = SR * (b_ih[j] + b_hh[j]);
    const float bias_z = SR * (b_ih[8 + j] + b_hh[8 + j]);
    const float bni_s  = SN * b_ih[16 + j];
    const float bnh_s  = SN * b_hh[16 + j];

    // lane L covers batch (blockIdx<<3)+(L>>3), column L&7: linear index
    // (blockIdx<<6)+L into every (B,H) slice for BOTH x loads and out stores.
    const float* xq = x + (blockIdx.x << 6) + lane;
    float* op = out + (blockIdx.x << 6) + lane;
    float* hlast = out + (size_t)SS * BB * HH + (blockIdx.x << 6) + lane;

    float xA[8], xB[8];   // distributed x: 1 dword/lane/step (16 VGPRs total)

    // prologue: groups 0 -> A, 1 -> B; retire A's 8 (B's 8 stay in flight)
    LOADG(xA, 0);
    LOADG(xB, 1);
    WAITV(8);

    float h = 0.0f;
    f32x2 hv2[4] = {{0,0},{0,0},{0,0},{0,0}};
    float xr[8], xz[8], xn[8];

    // Steady state at each WAITV(16): newest 16 = this group's 8 stores +
    // next-next group's 8 loads; everything older (other buffer's loads) done.
    for (int g = 0; g < 124; g += 2) {
        GROUP(xA, g * 8);
        LOADG(xA, g + 2);
        WAITV(16);
        GROUP(xB, (g + 1) * 8);
        LOADG(xB, g + 3);
        WAITV(16);
    }
    GROUP(xA, 992);  LOADG(xA, 126); WAITV(16);
    GROUP(xB, 1000); LOADG(xB, 127); WAITV(16);
    GROUP(xA, 1008); WAITV(8);
    GROUP(xB, 1016);

    *hlast = h;
}

extern "C" void kernel_launch(void* const* d_in, const int* in_sizes, int n_in,
                              void* d_out, int out_size, void* d_ws, size_t ws_size,
                              hipStream_t stream) {
    const float* x    = (const float*)d_in[0];
    const float* w_ih = (const float*)d_in[1];
    const float* w_hh = (const float*)d_in[2];
    const float* b_ih = (const float*)d_in[3];
    const float* b_hh = (const float*)d_in[4];
    float* out = (float*)d_out;
    gru_kernel<<<BB / 8, 64, 0, stream>>>(x, w_ih, w_hh, b_ih, b_hh, out);
}